// Round 16
// baseline (18217.534 us; speedup 1.0000x reference)
//
#include <hip/hip_runtime.h>
#include <math.h>

#define TT 512
#define BB 256
#define EE 300
#define KK 9
#define HH 256
#define GG 1024
#define CHS 64
#define NCH (TT/CHS)

// ws offsets (floats)
#define OFF_XG ((size_t)0)                          // 2*CHS*BB*GG
#define OFF_WT (OFF_XG + (size_t)2*CHS*BB*GG)       // 2*64*1024 float4
#define OFF_HS (OFF_WT + (size_t)2*64*1024*4)
#define OFF_CS (OFF_HS + (size_t)2*BB*HH)
#define OFF_EF (OFF_CS + (size_t)2*BB*HH)
#define OFF_EB (OFF_EF + (size_t)BB*TT*KK)
#define OFF_ND (OFF_EB + (size_t)BB*TT*KK)

// NOTE: macro params must NOT be named x/y/z/w (round-6 preprocessor bug).
#define DOT4(a_,b_) ((a_).x*(b_).x + (a_).y*(b_).y + (a_).z*(b_).z + (a_).w*(b_).w)
#define FMA4(acc_, w_, h_) do { \
    acc_ = fmaf((w_).x, (h_).x, acc_); \
    acc_ = fmaf((w_).y, (h_).y, acc_); \
    acc_ = fmaf((w_).z, (h_).z, acc_); \
    acc_ = fmaf((w_).w, (h_).w, acc_); } while (0)

// ---------------- W_hh transpose/pack: Wt[dir][k4][row] (k-major; r10: native-layout
// lane-scattered reads collapse to HBM — keep packed) ----------------
__global__ __launch_bounds__(1024) void wtrans_kernel(
    const float* __restrict__ Wf, const float* __restrict__ Wb, float* __restrict__ Wt)
{
  int idx = blockIdx.x * 1024 + threadIdx.x;
  int dir = idx >> 16;
  int r   = (idx >> 6) & 1023;
  int k4  = idx & 63;
  const float* W = dir ? Wb : Wf;
  float4 v = *(const float4*)&W[(size_t)r * HH + k4 * 4];
  ((float4*)Wt)[(size_t)dir * 65536 + (size_t)k4 * 1024 + r] = v;
}

// ---------------- xg chunk GEMM: grid 512 (r14 verbatim — ~75% of f32 peak) ----------------
__global__ __launch_bounds__(256) void gemm_xg_kernel(
    const int* __restrict__ ids, const float* __restrict__ emb,
    const float* __restrict__ W_ih_f, const float* __restrict__ W_ih_b,
    const float* __restrict__ b_f, const float* __restrict__ b_b,
    float* __restrict__ xgc, int ci)
{
  __shared__ float As[60][132];
  __shared__ float Ws[60][132];
  __shared__ int tokid[128];
  const int tid = threadIdx.x;
  const int bx  = blockIdx.x;
  const int dir = bx >> 8;
  const int rem = bx & 255;
  const int rt  = rem & 127;
  const int nth = rem >> 7;            // nt half: 0 -> tiles 0..3, 1 -> tiles 4..7
  const float* W_ih = dir ? W_ih_b : W_ih_f;
  const float* bias = dir ? b_b : b_f;

  if (tid < 128) {
    int m = rt * 128 + tid;
    int sidx = ci * CHS + (m >> 8);
    int t = dir ? (TT - 1 - sidx) : sidx;
    tokid[tid] = ids[t * BB + (m & 255)];
  }
  __syncthreads();

  const int ty = tid >> 4, tx = tid & 15;
  for (int nt = nth * 4; nt < nth * 4 + 4; ++nt) {
    float acc[8][8];
    #pragma unroll
    for (int a_ = 0; a_ < 8; ++a_)
      #pragma unroll
      for (int b_ = 0; b_ < 8; ++b_) acc[a_][b_] = 0.f;

    for (int kc = 0; kc < 5; ++kc) {
      __syncthreads();
      for (int i = tid; i < 128 * 15; i += 256) {
        int mm = i / 15, kq = i - mm * 15;
        float4 v = *(const float4*)&emb[(size_t)tokid[mm] * EE + kc * 60 + kq * 4];
        As[kq*4+0][mm] = v.x; As[kq*4+1][mm] = v.y;
        As[kq*4+2][mm] = v.z; As[kq*4+3][mm] = v.w;
      }
      for (int i = tid; i < 128 * 15; i += 256) {
        int nn = i / 15, kq = i - nn * 15;
        float4 v = *(const float4*)&W_ih[(size_t)(nt*128+nn) * EE + kc * 60 + kq * 4];
        Ws[kq*4+0][nn] = v.x; Ws[kq*4+1][nn] = v.y;
        Ws[kq*4+2][nn] = v.z; Ws[kq*4+3][nn] = v.w;
      }
      __syncthreads();
      for (int kk = 0; kk < 60; ++kk) {
        float4 a0 = *(const float4*)&As[kk][ty*8];
        float4 a1 = *(const float4*)&As[kk][ty*8+4];
        float4 w0 = *(const float4*)&Ws[kk][tx*8];
        float4 w1 = *(const float4*)&Ws[kk][tx*8+4];
        float av[8]  = {a0.x,a0.y,a0.z,a0.w,a1.x,a1.y,a1.z,a1.w};
        float wv8[8] = {w0.x,w0.y,w0.z,w0.w,w1.x,w1.y,w1.z,w1.w};
        #pragma unroll
        for (int im = 0; im < 8; ++im)
          #pragma unroll
          for (int in = 0; in < 8; ++in) acc[im][in] += av[im] * wv8[in];
      }
    }
    #pragma unroll
    for (int im = 0; im < 8; ++im) {
      int m = ty*8 + im;
      int n = nt*128 + tx*8;
      float4 o0, o1;
      o0.x = acc[im][0] + bias[n+0]; o0.y = acc[im][1] + bias[n+1];
      o0.z = acc[im][2] + bias[n+2]; o0.w = acc[im][3] + bias[n+3];
      o1.x = acc[im][4] + bias[n+4]; o1.y = acc[im][5] + bias[n+5];
      o1.z = acc[im][6] + bias[n+6]; o1.w = acc[im][7] + bias[n+7];
      float* dst = &xgc[(size_t)(dir*16384 + rt*128 + m) * GG + n];
      *(float4*)dst = o0; *(float4*)(dst+4) = o1;
    }
  }
}

// ---------------- recurrence: r14 structure + LDS-only W residency (iters 3-4) ----------------
// W is step-invariant: k-iterations 3,4 are staged once per chunk into LDS (128 KB,
// kseg blocks padded +2 float4 -> 32B bank skew); iters 0-2 and 5-15 streamed with the
// proven depth-2 named-register prefetch. NO new per-thread arrays (r13/r15 spill lesson).
// FMA order unchanged (i ascending) -> bit-identical gates.
__global__ __launch_bounds__(1024, 1) void rec_chunk_kernel(
    const float* __restrict__ xgc, const float* __restrict__ Wt,
    const int* __restrict__ lens,
    float* __restrict__ hst, float* __restrict__ cst,
    float* __restrict__ emisf, float* __restrict__ emisb,
    const float* __restrict__ W_out, const float* __restrict__ b_out, int ci)
{
  __shared__ __align__(16) float hring[2][2][272];   // skew: float k at k+(k>>6)*4
  __shared__ __align__(16) float Wo[KK][256];
  __shared__ __align__(16) float4 WL[2 * 4104];      // iters 3-4: [j][kseg(pad 1026)][row]

  const int tid  = threadIdx.x;
  const int bid  = blockIdx.x;
  const int dir  = (bid & 7) >> 2;              // XCD-partitioned (perf-only heuristic)
  const int grp  = (bid >> 3) * 4 + (bid & 3);
  const int b0   = grp * 2;
  const int lane = tid & 63;
  const int wv   = tid >> 6;
  const int rg   = wv * 16 + (lane & 15);
  const int kseg = (lane >> 4) & 3;
  const bool cellLane = (lane & 48) == 0;
  float* emis = dir ? emisb : emisf;

  for (int i = tid; i < KK * 64; i += 1024) {
    int k = i >> 6, q = i & 63;
    *(float4*)&Wo[k][q*4] = *(const float4*)&W_out[(size_t)k * 512 + dir*256 + q*4];
  }

  // stage LDS-resident W slices (k-iterations 3 and 4), coalesced, once per chunk
  {
    const float4* wtd = (const float4*)Wt + (size_t)dir * 65536;
    for (int i = tid; i < 8192; i += 1024) {
      int j   = i >> 12;
      int ks  = (i >> 10) & 3;
      int row = i & 1023;
      WL[j * 4104 + ks * 1026 + row] = wtd[(size_t)(ks * 16 + 3 + j) * 1024 + row];
    }
  }

  int eb = 0, ek = 0, es = 0;
  const bool edo = tid < 2 * KK * 16;
  if (edo) { int q = tid; eb = q / 144; q -= eb * 144; ek = q >> 4; es = q & 15; }
  const float ebias = (edo && dir == 0) ? b_out[ek] : 0.f;

  int len2[2];
  #pragma unroll
  for (int b = 0; b < 2; ++b) len2[b] = lens[b0 + b];

  float creg[2] = {0.f,0.f}, hreg[2] = {0.f,0.f};
  if (cellLane) {
    if (ci > 0) {
      #pragma unroll
      for (int b = 0; b < 2; ++b) {
        hreg[b] = hst[((size_t)dir*BB + b0 + b) * HH + rg];
        creg[b] = cst[((size_t)dir*BB + b0 + b) * HH + rg];
      }
    }
    #pragma unroll
    for (int b = 0; b < 2; ++b)
      hring[0][b][rg + ((rg >> 6) << 2)] = hreg[b];
  }
  __syncthreads();

  const float4* wp = (const float4*)Wt + (size_t)dir * 65536
                   + (size_t)(kseg * 16) * 1024 + rg;
  const int wlbase = kseg * 1026 + rg;

  for (int sl = 0; sl < CHS; ++sl) {
    const int s = ci * CHS + sl;
    const int t = dir ? (TT - 1 - s) : s;
    const int cur = sl & 1, nxt = cur ^ 1;

    // xg prefetch (cell lanes; nontemporal — read-once stream)
    float xv[4][2];
    if (cellLane) {
      const float* xb = xgc + ((size_t)dir*(CHS*BB) + (size_t)sl*BB + b0) * GG + rg;
      #pragma unroll
      for (int q = 0; q < 4; ++q)
        #pragma unroll
        for (int b = 0; b < 2; ++b)
          xv[q][b] = __builtin_nontemporal_load(&xb[(size_t)b * GG + q * 256]);
    }

    float acc[4][2];
    #pragma unroll
    for (int q = 0; q < 4; ++q) { acc[q][0] = 0.f; acc[q][1] = 0.f; }

    const float4* hb = (const float4*)&hring[0][0][0] + cur * (2*68) + kseg * 17;

    // ---- i = 0..2: streamed, depth-2 named-register prefetch ----
    float4 w0 = wp[0], w1 = wp[256], w2 = wp[512], w3 = wp[768];
    #pragma unroll
    for (int i = 0; i < 2; ++i) {
      const float4* wn = wp + (size_t)(i + 1) * 1024;
      float4 n0 = wn[0], n1 = wn[256], n2 = wn[512], n3 = wn[768];
      float4 h0 = hb[i], h1 = hb[68 + i];
      FMA4(acc[0][0], w0, h0); FMA4(acc[0][1], w0, h1);
      FMA4(acc[1][0], w1, h0); FMA4(acc[1][1], w1, h1);
      FMA4(acc[2][0], w2, h0); FMA4(acc[2][1], w2, h1);
      FMA4(acc[3][0], w3, h0); FMA4(acc[3][1], w3, h1);
      w0 = n0; w1 = n1; w2 = n2; w3 = n3;
    }
    {
      // i = 2 (last before LDS-resident span); prefetch i=5 (next streamed)
      const float4* wn = wp + (size_t)5 * 1024;
      float4 n0 = wn[0], n1 = wn[256], n2 = wn[512], n3 = wn[768];
      float4 h0 = hb[2], h1 = hb[68 + 2];
      FMA4(acc[0][0], w0, h0); FMA4(acc[0][1], w0, h1);
      FMA4(acc[1][0], w1, h0); FMA4(acc[1][1], w1, h1);
      FMA4(acc[2][0], w2, h0); FMA4(acc[2][1], w2, h1);
      FMA4(acc[3][0], w3, h0); FMA4(acc[3][1], w3, h1);
      w0 = n0; w1 = n1; w2 = n2; w3 = n3;
    }
    // ---- i = 3..4: LDS-resident ----
    #pragma unroll
    for (int i = 3; i < 5; ++i) {
      const float4* wl = &WL[(i - 3) * 4104 + wlbase];
      float4 v0 = wl[0], v1 = wl[256], v2 = wl[512], v3 = wl[768];
      float4 h0 = hb[i], h1 = hb[68 + i];
      FMA4(acc[0][0], v0, h0); FMA4(acc[0][1], v0, h1);
      FMA4(acc[1][0], v1, h0); FMA4(acc[1][1], v1, h1);
      FMA4(acc[2][0], v2, h0); FMA4(acc[2][1], v2, h1);
      FMA4(acc[3][0], v3, h0); FMA4(acc[3][1], v3, h1);
    }
    // ---- i = 5..15: streamed, depth-2 named-register prefetch ----
    #pragma unroll
    for (int i = 5; i < 15; ++i) {
      const float4* wn = wp + (size_t)(i + 1) * 1024;
      float4 n0 = wn[0], n1 = wn[256], n2 = wn[512], n3 = wn[768];
      float4 h0 = hb[i], h1 = hb[68 + i];
      FMA4(acc[0][0], w0, h0); FMA4(acc[0][1], w0, h1);
      FMA4(acc[1][0], w1, h0); FMA4(acc[1][1], w1, h1);
      FMA4(acc[2][0], w2, h0); FMA4(acc[2][1], w2, h1);
      FMA4(acc[3][0], w3, h0); FMA4(acc[3][1], w3, h1);
      w0 = n0; w1 = n1; w2 = n2; w3 = n3;
    }
    {
      float4 h0 = hb[15], h1 = hb[68 + 15];
      FMA4(acc[0][0], w0, h0); FMA4(acc[0][1], w0, h1);
      FMA4(acc[1][0], w1, h0); FMA4(acc[1][1], w1, h1);
      FMA4(acc[2][0], w2, h0); FMA4(acc[2][1], w2, h1);
      FMA4(acc[3][0], w3, h0); FMA4(acc[3][1], w3, h1);
    }

    // ---- reduce k-slices across lane bits 4-5 ----
    #pragma unroll
    for (int q = 0; q < 4; ++q)
      #pragma unroll
      for (int b = 0; b < 2; ++b) {
        float v = acc[q][b];
        v += __shfl_xor(v, 16);
        v += __shfl_xor(v, 32);
        acc[q][b] = v;
      }

    // ---- cell update (lanes l<16 hold full gates for their rg) ----
    if (cellLane) {
      #pragma unroll
      for (int b = 0; b < 2; ++b) {
        float gi = acc[0][b] + xv[0][b];
        float gf = acc[1][b] + xv[1][b];
        float gg = acc[2][b] + xv[2][b];
        float go = acc[3][b] + xv[3][b];
        float si = 1.f / (1.f + expf(-gi));
        float sf = 1.f / (1.f + expf(-gf));
        float so = 1.f / (1.f + expf(-go));
        float cn = sf * creg[b] + si * tanhf(gg);
        float hn = so * tanhf(cn);
        bool m = t < len2[b];
        hreg[b] = m ? hn : hreg[b];
        creg[b] = m ? cn : creg[b];
        hring[nxt][b][rg + ((rg >> 6) << 2)] = hreg[b];
      }
    }
    __syncthreads();

    // ---- fused emission for this timestep (reads hring[nxt]); NT store ----
    if (edo) {
      float r = 0.f;
      #pragma unroll
      for (int i4 = 0; i4 < 4; ++i4) {
        float4 h4 = *(const float4*)&hring[nxt][eb][es*4 + i4*68];
        float4 w4 = *(const float4*)&Wo[ek][es*4 + i4*64];
        r += DOT4(h4, w4);
      }
      r += __shfl_xor(r, 8); r += __shfl_xor(r, 4);
      r += __shfl_xor(r, 2); r += __shfl_xor(r, 1);
      if (es == 0)
        __builtin_nontemporal_store(r + ebias,
            &emis[((size_t)(b0 + eb) * TT + t) * KK + ek]);
    }
  }

  if (cellLane) {
    #pragma unroll
    for (int b = 0; b < 2; ++b) {
      hst[((size_t)dir*BB + b0 + b) * HH + rg] = hreg[b];
      cst[((size_t)dir*BB + b0 + b) * HH + rg] = creg[b];
    }
  }
}

// ---------------- CRF (identical numerics to rounds 1-15) ----------------
__global__ __launch_bounds__(64) void crf_kernel(
    const float* __restrict__ emis_f, const float* __restrict__ emis_b2,
    const int* __restrict__ labels, const int* __restrict__ lens,
    const float* __restrict__ start_trans, const float* __restrict__ end_trans,
    const float* __restrict__ trans,
    float* __restrict__ numden, float* __restrict__ outp)
{
  const int b = blockIdx.x;
  const int lane = threadIdx.x;
  __shared__ __align__(16) float em[TT * KK];
  __shared__ unsigned char hist[TT * KK];
  const float4* ef = (const float4*)(emis_f + (size_t)b * TT * KK);
  const float4* eb = (const float4*)(emis_b2 + (size_t)b * TT * KK);
  for (int i = lane; i < TT*KK/4; i += 64) {
    float4 a = ef[i], c = eb[i];
    float4 o; o.x = a.x+c.x; o.y = a.y+c.y; o.z = a.z+c.z; o.w = a.w+c.w;
    ((float4*)em)[i] = o;
  }
  const int len = lens[b];
  const int k = lane < KK ? lane : KK-1;
  float tc[KK];
  #pragma unroll
  for (int jj = 0; jj < KK; ++jj) tc[jj] = trans[jj*KK + k];
  __syncthreads();

  float nacc = 0.f;
  for (int t = lane; t < TT; t += 64) {
    int lt = labels[t*BB + b];
    if (t == 0) nacc += start_trans[lt] + em[lt];
    else if (t < len) nacc += trans[labels[(t-1)*BB + b]*KK + lt] + em[t*KK + lt];
  }
  if (lane == 0) nacc += end_trans[labels[(size_t)(len-1)*BB + b]];
  #pragma unroll
  for (int off = 32; off; off >>= 1) nacc += __shfl_down(nacc, off);

  float alpha[KK], score[KK];
  #pragma unroll
  for (int jj = 0; jj < KK; ++jj) {
    float v = start_trans[jj] + em[jj];
    alpha[jj] = v; score[jj] = v;
  }
  for (int t = 1; t < TT; ++t) {
    float av[KK]; float mx = -1e30f;
    #pragma unroll
    for (int jj = 0; jj < KK; ++jj) { av[jj] = alpha[jj] + tc[jj]; mx = fmaxf(mx, av[jj]); }
    float ssum = 0.f;
    #pragma unroll
    for (int jj = 0; jj < KK; ++jj) ssum += expf(av[jj] - mx);
    float e_tk = em[t*KK + k];
    float na = mx + logf(ssum) + e_tk;
    float best = -1e30f; int bj = 0;
    #pragma unroll
    for (int jj = 0; jj < KK; ++jj) {
      float sv = score[jj] + tc[jj];
      if (sv > best) { best = sv; bj = jj; }
    }
    float ns = best + e_tk;
    bool msk = t < len;
    na = msk ? na : alpha[k];
    ns = msk ? ns : score[k];
    if (lane < KK) hist[(t-1)*KK + lane] = (unsigned char)bj;
    #pragma unroll
    for (int jj = 0; jj < KK; ++jj) { alpha[jj] = __shfl(na, jj); score[jj] = __shfl(ns, jj); }
  }
  float dm = -1e30f;
  #pragma unroll
  for (int jj = 0; jj < KK; ++jj) dm = fmaxf(dm, alpha[jj] + end_trans[jj]);
  float dsum = 0.f;
  #pragma unroll
  for (int jj = 0; jj < KK; ++jj) dsum += expf(alpha[jj] + end_trans[jj] - dm);
  float denom = dm + logf(dsum);
  int bl_ = 0; float bs = -1e30f;
  #pragma unroll
  for (int jj = 0; jj < KK; ++jj) {
    float v = score[jj] + end_trans[jj];
    if (v > bs) { bs = v; bl_ = jj; }
  }
  if (lane == 0) numden[b] = nacc - denom;
  __syncthreads();
  if (lane == 0) {
    int tag = bl_;
    outp[1 + (size_t)(TT-1)*BB + b] = ((TT-1) < len) ? (float)bl_ : 0.f;
    for (int s = TT-2; s >= 0; --s) {
      tag = ((s+1) < len) ? (int)hist[s*KK + tag] : bl_;
      outp[1 + (size_t)s*BB + b] = (s < len) ? (float)tag : 0.f;
    }
  }
}

__global__ __launch_bounds__(256) void loss_reduce_kernel(
    const float* __restrict__ numden, float* __restrict__ out)
{
  __shared__ float sh[256];
  int tid = threadIdx.x;
  sh[tid] = numden[tid];
  __syncthreads();
  for (int s = 128; s > 0; s >>= 1) {
    if (tid < s) sh[tid] += sh[tid + s];
    __syncthreads();
  }
  if (tid == 0) out[0] = -sh[0];
}

extern "C" void kernel_launch(void* const* d_in, const int* in_sizes, int n_in,
                              void* d_out, int out_size, void* d_ws, size_t ws_size,
                              hipStream_t stream)
{
  const int*   ids    = (const int*)d_in[0];
  const int*   lens   = (const int*)d_in[1];
  const int*   labels = (const int*)d_in[2];
  const float* emb    = (const float*)d_in[3];
  const float* W_ih_f = (const float*)d_in[4];
  const float* W_hh_f = (const float*)d_in[5];
  const float* b_f    = (const float*)d_in[6];
  const float* W_ih_b = (const float*)d_in[7];
  const float* W_hh_b = (const float*)d_in[8];
  const float* b_b    = (const float*)d_in[9];
  const float* W_out  = (const float*)d_in[10];
  const float* b_out  = (const float*)d_in[11];
  const float* s_tr   = (const float*)d_in[12];
  const float* e_tr   = (const float*)d_in[13];
  const float* trans  = (const float*)d_in[14];
  float* out = (float*)d_out;

  float* ws = (float*)d_ws;
  float* xgc    = ws + OFF_XG;
  float* Wt     = ws + OFF_WT;
  float* hst    = ws + OFF_HS;
  float* cst    = ws + OFF_CS;
  float* emis_f = ws + OFF_EF;
  float* emis_b = ws + OFF_EB;
  float* numden = ws + OFF_ND;

  wtrans_kernel<<<128, 1024, 0, stream>>>(W_hh_f, W_hh_b, Wt);

  for (int ci = 0; ci < NCH; ++ci) {
    gemm_xg_kernel<<<512, 256, 0, stream>>>(ids, emb, W_ih_f, W_ih_b, b_f, b_b, xgc, ci);
    rec_chunk_kernel<<<256, 1024, 0, stream>>>(xgc, Wt, lens, hst, cst,
                                               emis_f, emis_b, W_out, b_out, ci);
  }

  crf_kernel<<<BB, 64, 0, stream>>>(emis_f, emis_b, labels, lens, s_tr, e_tr, trans, numden, out);
  loss_reduce_kernel<<<1, 256, 0, stream>>>(numden, out);
}

// Round 17
// 8960.033 us; speedup vs baseline: 2.0332x; 2.0332x over previous
//
#include <hip/hip_runtime.h>
#include <math.h>

#define TT 512
#define BB 256
#define EE 300
#define KK 9
#define HH 256
#define GG 1024
#define CHS 64
#define NCH (TT/CHS)

// ws offsets (floats)
#define OFF_XG ((size_t)0)                          // 2*CHS*BB*GG
#define OFF_WT (OFF_XG + (size_t)2*CHS*BB*GG)       // 2*64*1024 float4
#define OFF_HS (OFF_WT + (size_t)2*64*1024*4)
#define OFF_CS (OFF_HS + (size_t)2*BB*HH)
#define OFF_EF (OFF_CS + (size_t)2*BB*HH)
#define OFF_EB (OFF_EF + (size_t)BB*TT*KK)
#define OFF_ND (OFF_EB + (size_t)BB*TT*KK)

// NOTE: macro params must NOT be named x/y/z/w (round-6 preprocessor bug).
#define DOT4(a_,b_) ((a_).x*(b_).x + (a_).y*(b_).y + (a_).z*(b_).z + (a_).w*(b_).w)
#define FMA4(acc_, w_, h_) do { \
    acc_ = fmaf((w_).x, (h_).x, acc_); \
    acc_ = fmaf((w_).y, (h_).y, acc_); \
    acc_ = fmaf((w_).z, (h_).z, acc_); \
    acc_ = fmaf((w_).w, (h_).w, acc_); } while (0)

// ---------------- W_hh transpose/pack: Wt[dir][k4][row] (k-major; r10: native-layout
// lane-scattered reads collapse to HBM — keep packed) ----------------
__global__ __launch_bounds__(1024) void wtrans_kernel(
    const float* __restrict__ Wf, const float* __restrict__ Wb, float* __restrict__ Wt)
{
  int idx = blockIdx.x * 1024 + threadIdx.x;
  int dir = idx >> 16;
  int r   = (idx >> 6) & 1023;
  int k4  = idx & 63;
  const float* W = dir ? Wb : Wf;
  float4 v = *(const float4*)&W[(size_t)r * HH + k4 * 4];
  ((float4*)Wt)[(size_t)dir * 65536 + (size_t)k4 * 1024 + r] = v;
}

// ---------------- xg chunk GEMM: grid 512 (r14 verbatim — ~75% of f32 peak) ----------------
__global__ __launch_bounds__(256) void gemm_xg_kernel(
    const int* __restrict__ ids, const float* __restrict__ emb,
    const float* __restrict__ W_ih_f, const float* __restrict__ W_ih_b,
    const float* __restrict__ b_f, const float* __restrict__ b_b,
    float* __restrict__ xgc, int ci)
{
  __shared__ float As[60][132];
  __shared__ float Ws[60][132];
  __shared__ int tokid[128];
  const int tid = threadIdx.x;
  const int bx  = blockIdx.x;
  const int dir = bx >> 8;
  const int rem = bx & 255;
  const int rt  = rem & 127;
  const int nth = rem >> 7;            // nt half: 0 -> tiles 0..3, 1 -> tiles 4..7
  const float* W_ih = dir ? W_ih_b : W_ih_f;
  const float* bias = dir ? b_b : b_f;

  if (tid < 128) {
    int m = rt * 128 + tid;
    int sidx = ci * CHS + (m >> 8);
    int t = dir ? (TT - 1 - sidx) : sidx;
    tokid[tid] = ids[t * BB + (m & 255)];
  }
  __syncthreads();

  const int ty = tid >> 4, tx = tid & 15;
  for (int nt = nth * 4; nt < nth * 4 + 4; ++nt) {
    float acc[8][8];
    #pragma unroll
    for (int a_ = 0; a_ < 8; ++a_)
      #pragma unroll
      for (int b_ = 0; b_ < 8; ++b_) acc[a_][b_] = 0.f;

    for (int kc = 0; kc < 5; ++kc) {
      __syncthreads();
      for (int i = tid; i < 128 * 15; i += 256) {
        int mm = i / 15, kq = i - mm * 15;
        float4 v = *(const float4*)&emb[(size_t)tokid[mm] * EE + kc * 60 + kq * 4];
        As[kq*4+0][mm] = v.x; As[kq*4+1][mm] = v.y;
        As[kq*4+2][mm] = v.z; As[kq*4+3][mm] = v.w;
      }
      for (int i = tid; i < 128 * 15; i += 256) {
        int nn = i / 15, kq = i - nn * 15;
        float4 v = *(const float4*)&W_ih[(size_t)(nt*128+nn) * EE + kc * 60 + kq * 4];
        Ws[kq*4+0][nn] = v.x; Ws[kq*4+1][nn] = v.y;
        Ws[kq*4+2][nn] = v.z; Ws[kq*4+3][nn] = v.w;
      }
      __syncthreads();
      for (int kk = 0; kk < 60; ++kk) {
        float4 a0 = *(const float4*)&As[kk][ty*8];
        float4 a1 = *(const float4*)&As[kk][ty*8+4];
        float4 w0 = *(const float4*)&Ws[kk][tx*8];
        float4 w1 = *(const float4*)&Ws[kk][tx*8+4];
        float av[8]  = {a0.x,a0.y,a0.z,a0.w,a1.x,a1.y,a1.z,a1.w};
        float wv8[8] = {w0.x,w0.y,w0.z,w0.w,w1.x,w1.y,w1.z,w1.w};
        #pragma unroll
        for (int im = 0; im < 8; ++im)
          #pragma unroll
          for (int in = 0; in < 8; ++in) acc[im][in] += av[im] * wv8[in];
      }
    }
    #pragma unroll
    for (int im = 0; im < 8; ++im) {
      int m = ty*8 + im;
      int n = nt*128 + tx*8;
      float4 o0, o1;
      o0.x = acc[im][0] + bias[n+0]; o0.y = acc[im][1] + bias[n+1];
      o0.z = acc[im][2] + bias[n+2]; o0.w = acc[im][3] + bias[n+3];
      o1.x = acc[im][4] + bias[n+4]; o1.y = acc[im][5] + bias[n+5];
      o1.z = acc[im][6] + bias[n+6]; o1.w = acc[im][7] + bias[n+7];
      float* dst = &xgc[(size_t)(dir*16384 + rt*128 + m) * GG + n];
      *(float4*)dst = o0; *(float4*)(dst+4) = o1;
    }
  }
}

// ---------------- recurrence: 4 batches/block, 128 blocks, depth-2 W prefetch ----------------
// Halves per-XCD W egress vs r14 (16 blocks/XCD x 1MB = 3.7us floor). amdgpu_waves_per_eu(4,4)
// unlocks a 128-VGPR budget (hipcc's default 64-cap caused r15/r16 spills). Thread (rg,kseg)
// owns 4 gate rows x 64k x 4 batches; partials via __shfl_xor(16/32); one barrier/step.
__global__ __launch_bounds__(1024)
__attribute__((amdgpu_waves_per_eu(4, 4)))
void rec_chunk_kernel(
    const float* __restrict__ xgc, const float* __restrict__ Wt,
    const int* __restrict__ lens,
    float* __restrict__ hst, float* __restrict__ cst,
    float* __restrict__ emisf, float* __restrict__ emisb,
    const float* __restrict__ W_out, const float* __restrict__ b_out, int ci)
{
  __shared__ __align__(16) float hring[2][4][272];   // skew: float k at k+(k>>6)*4
  __shared__ __align__(16) float Wo[KK][256];

  const int tid  = threadIdx.x;
  const int bid  = blockIdx.x;                  // 0..127
  const int dir  = (bid & 7) >> 2;              // XCD-partitioned: one dir per XCD
  const int grp  = (bid >> 3) * 4 + (bid & 3);  // 0..63 within dir
  const int b0   = grp * 4;
  const int lane = tid & 63;
  const int wv   = tid >> 6;
  const int rg   = wv * 16 + (lane & 15);       // gate column j (0..255)
  const int kseg = (lane >> 4) & 3;             // k-slice of 64
  const bool cellLane = (lane & 48) == 0;
  float* emis = dir ? emisb : emisf;

  for (int i = tid; i < KK * 64; i += 1024) {
    int k = i >> 6, q = i & 63;
    *(float4*)&Wo[k][q*4] = *(const float4*)&W_out[(size_t)k * 512 + dir*256 + q*4];
  }

  // emission roles: 576 threads = (eb<4, ek<9, es<16)
  int eb = 0, ek = 0, es = 0;
  const bool edo = tid < 4 * KK * 16;
  if (edo) { int q = tid; eb = q / 144; q -= eb * 144; ek = q >> 4; es = q & 15; }
  const float ebias = (edo && dir == 0) ? b_out[ek] : 0.f;

  int len4[4];
  #pragma unroll
  for (int b = 0; b < 4; ++b) len4[b] = lens[b0 + b];

  float creg[4] = {0.f,0.f,0.f,0.f}, hreg[4] = {0.f,0.f,0.f,0.f};
  if (cellLane) {
    if (ci > 0) {
      #pragma unroll
      for (int b = 0; b < 4; ++b) {
        hreg[b] = hst[((size_t)dir*BB + b0 + b) * HH + rg];
        creg[b] = cst[((size_t)dir*BB + b0 + b) * HH + rg];
      }
    }
    #pragma unroll
    for (int b = 0; b < 4; ++b)
      hring[0][b][rg + ((rg >> 6) << 2)] = hreg[b];
  }
  __syncthreads();

  const float4* wp = (const float4*)Wt + (size_t)dir * 65536
                   + (size_t)(kseg * 16) * 1024 + rg;

  for (int sl = 0; sl < CHS; ++sl) {
    const int s = ci * CHS + sl;
    const int t = dir ? (TT - 1 - s) : s;
    const int cur = sl & 1, nxt = cur ^ 1;

    // xg prefetch (cell lanes; nontemporal — read-once stream)
    float xv[4][4];
    if (cellLane) {
      const float* xb = xgc + ((size_t)dir*(CHS*BB) + (size_t)sl*BB + b0) * GG + rg;
      #pragma unroll
      for (int q = 0; q < 4; ++q)
        #pragma unroll
        for (int b = 0; b < 4; ++b)
          xv[q][b] = __builtin_nontemporal_load(&xb[(size_t)b * GG + q * 256]);
    }

    // ---- GEMM over this thread's 64-k slice x 4 batches, depth-2 named prefetch ----
    float acc[4][4];
    #pragma unroll
    for (int q = 0; q < 4; ++q)
      #pragma unroll
      for (int b = 0; b < 4; ++b) acc[q][b] = 0.f;

    const float4* hb = (const float4*)&hring[0][0][0] + cur * (4*68) + kseg * 17;
    float4 w0 = wp[0], w1 = wp[256], w2 = wp[512], w3 = wp[768];
    #pragma unroll 5
    for (int i = 0; i < 15; ++i) {
      const float4* wn = wp + (size_t)(i + 1) * 1024;
      float4 n0 = wn[0], n1 = wn[256], n2 = wn[512], n3 = wn[768];
      float4 h0 = hb[i], h1 = hb[68 + i], h2 = hb[136 + i], h3 = hb[204 + i];
      FMA4(acc[0][0], w0, h0); FMA4(acc[0][1], w0, h1); FMA4(acc[0][2], w0, h2); FMA4(acc[0][3], w0, h3);
      FMA4(acc[1][0], w1, h0); FMA4(acc[1][1], w1, h1); FMA4(acc[1][2], w1, h2); FMA4(acc[1][3], w1, h3);
      FMA4(acc[2][0], w2, h0); FMA4(acc[2][1], w2, h1); FMA4(acc[2][2], w2, h2); FMA4(acc[2][3], w2, h3);
      FMA4(acc[3][0], w3, h0); FMA4(acc[3][1], w3, h1); FMA4(acc[3][2], w3, h2); FMA4(acc[3][3], w3, h3);
      w0 = n0; w1 = n1; w2 = n2; w3 = n3;
    }
    {
      float4 h0 = hb[15], h1 = hb[68 + 15], h2 = hb[136 + 15], h3 = hb[204 + 15];
      FMA4(acc[0][0], w0, h0); FMA4(acc[0][1], w0, h1); FMA4(acc[0][2], w0, h2); FMA4(acc[0][3], w0, h3);
      FMA4(acc[1][0], w1, h0); FMA4(acc[1][1], w1, h1); FMA4(acc[1][2], w1, h2); FMA4(acc[1][3], w1, h3);
      FMA4(acc[2][0], w2, h0); FMA4(acc[2][1], w2, h1); FMA4(acc[2][2], w2, h2); FMA4(acc[2][3], w2, h3);
      FMA4(acc[3][0], w3, h0); FMA4(acc[3][1], w3, h1); FMA4(acc[3][2], w3, h2); FMA4(acc[3][3], w3, h3);
    }

    // ---- reduce k-slices across lane bits 4-5 ----
    #pragma unroll
    for (int q = 0; q < 4; ++q)
      #pragma unroll
      for (int b = 0; b < 4; ++b) {
        float v = acc[q][b];
        v += __shfl_xor(v, 16);
        v += __shfl_xor(v, 32);
        acc[q][b] = v;
      }

    // ---- cell update (lanes l<16 hold full gates for their rg) ----
    if (cellLane) {
      #pragma unroll
      for (int b = 0; b < 4; ++b) {
        float gi = acc[0][b] + xv[0][b];
        float gf = acc[1][b] + xv[1][b];
        float gg = acc[2][b] + xv[2][b];
        float go = acc[3][b] + xv[3][b];
        float si = 1.f / (1.f + expf(-gi));
        float sf = 1.f / (1.f + expf(-gf));
        float so = 1.f / (1.f + expf(-go));
        float cn = sf * creg[b] + si * tanhf(gg);
        float hn = so * tanhf(cn);
        bool m = t < len4[b];
        hreg[b] = m ? hn : hreg[b];
        creg[b] = m ? cn : creg[b];
        hring[nxt][b][rg + ((rg >> 6) << 2)] = hreg[b];
      }
    }
    __syncthreads();

    // ---- fused emission for this timestep (reads hring[nxt]); NT store ----
    if (edo) {
      float r = 0.f;
      #pragma unroll
      for (int i4 = 0; i4 < 4; ++i4) {
        float4 h4 = *(const float4*)&hring[nxt][eb][es*4 + i4*68];
        float4 w4 = *(const float4*)&Wo[ek][es*4 + i4*64];
        r += DOT4(h4, w4);
      }
      r += __shfl_xor(r, 8); r += __shfl_xor(r, 4);
      r += __shfl_xor(r, 2); r += __shfl_xor(r, 1);
      if (es == 0)
        __builtin_nontemporal_store(r + ebias,
            &emis[((size_t)(b0 + eb) * TT + t) * KK + ek]);
    }
  }

  if (cellLane) {
    #pragma unroll
    for (int b = 0; b < 4; ++b) {
      hst[((size_t)dir*BB + b0 + b) * HH + rg] = hreg[b];
      cst[((size_t)dir*BB + b0 + b) * HH + rg] = creg[b];
    }
  }
}

// ---------------- CRF (identical numerics to rounds 1-16) ----------------
__global__ __launch_bounds__(64) void crf_kernel(
    const float* __restrict__ emis_f, const float* __restrict__ emis_b2,
    const int* __restrict__ labels, const int* __restrict__ lens,
    const float* __restrict__ start_trans, const float* __restrict__ end_trans,
    const float* __restrict__ trans,
    float* __restrict__ numden, float* __restrict__ outp)
{
  const int b = blockIdx.x;
  const int lane = threadIdx.x;
  __shared__ __align__(16) float em[TT * KK];
  __shared__ unsigned char hist[TT * KK];
  const float4* ef = (const float4*)(emis_f + (size_t)b * TT * KK);
  const float4* eb = (const float4*)(emis_b2 + (size_t)b * TT * KK);
  for (int i = lane; i < TT*KK/4; i += 64) {
    float4 a = ef[i], c = eb[i];
    float4 o; o.x = a.x+c.x; o.y = a.y+c.y; o.z = a.z+c.z; o.w = a.w+c.w;
    ((float4*)em)[i] = o;
  }
  const int len = lens[b];
  const int k = lane < KK ? lane : KK-1;
  float tc[KK];
  #pragma unroll
  for (int jj = 0; jj < KK; ++jj) tc[jj] = trans[jj*KK + k];
  __syncthreads();

  float nacc = 0.f;
  for (int t = lane; t < TT; t += 64) {
    int lt = labels[t*BB + b];
    if (t == 0) nacc += start_trans[lt] + em[lt];
    else if (t < len) nacc += trans[labels[(t-1)*BB + b]*KK + lt] + em[t*KK + lt];
  }
  if (lane == 0) nacc += end_trans[labels[(size_t)(len-1)*BB + b]];
  #pragma unroll
  for (int off = 32; off; off >>= 1) nacc += __shfl_down(nacc, off);

  float alpha[KK], score[KK];
  #pragma unroll
  for (int jj = 0; jj < KK; ++jj) {
    float v = start_trans[jj] + em[jj];
    alpha[jj] = v; score[jj] = v;
  }
  for (int t = 1; t < TT; ++t) {
    float av[KK]; float mx = -1e30f;
    #pragma unroll
    for (int jj = 0; jj < KK; ++jj) { av[jj] = alpha[jj] + tc[jj]; mx = fmaxf(mx, av[jj]); }
    float ssum = 0.f;
    #pragma unroll
    for (int jj = 0; jj < KK; ++jj) ssum += expf(av[jj] - mx);
    float e_tk = em[t*KK + k];
    float na = mx + logf(ssum) + e_tk;
    float best = -1e30f; int bj = 0;
    #pragma unroll
    for (int jj = 0; jj < KK; ++jj) {
      float sv = score[jj] + tc[jj];
      if (sv > best) { best = sv; bj = jj; }
    }
    float ns = best + e_tk;
    bool msk = t < len;
    na = msk ? na : alpha[k];
    ns = msk ? ns : score[k];
    if (lane < KK) hist[(t-1)*KK + lane] = (unsigned char)bj;
    #pragma unroll
    for (int jj = 0; jj < KK; ++jj) { alpha[jj] = __shfl(na, jj); score[jj] = __shfl(ns, jj); }
  }
  float dm = -1e30f;
  #pragma unroll
  for (int jj = 0; jj < KK; ++jj) dm = fmaxf(dm, alpha[jj] + end_trans[jj]);
  float dsum = 0.f;
  #pragma unroll
  for (int jj = 0; jj < KK; ++jj) dsum += expf(alpha[jj] + end_trans[jj] - dm);
  float denom = dm + logf(dsum);
  int bl_ = 0; float bs = -1e30f;
  #pragma unroll
  for (int jj = 0; jj < KK; ++jj) {
    float v = score[jj] + end_trans[jj];
    if (v > bs) { bs = v; bl_ = jj; }
  }
  if (lane == 0) numden[b] = nacc - denom;
  __syncthreads();
  if (lane == 0) {
    int tag = bl_;
    outp[1 + (size_t)(TT-1)*BB + b] = ((TT-1) < len) ? (float)bl_ : 0.f;
    for (int s = TT-2; s >= 0; --s) {
      tag = ((s+1) < len) ? (int)hist[s*KK + tag] : bl_;
      outp[1 + (size_t)s*BB + b] = (s < len) ? (float)tag : 0.f;
    }
  }
}

__global__ __launch_bounds__(256) void loss_reduce_kernel(
    const float* __restrict__ numden, float* __restrict__ out)
{
  __shared__ float sh[256];
  int tid = threadIdx.x;
  sh[tid] = numden[tid];
  __syncthreads();
  for (int s = 128; s > 0; s >>= 1) {
    if (tid < s) sh[tid] += sh[tid + s];
    __syncthreads();
  }
  if (tid == 0) out[0] = -sh[0];
}

extern "C" void kernel_launch(void* const* d_in, const int* in_sizes, int n_in,
                              void* d_out, int out_size, void* d_ws, size_t ws_size,
                              hipStream_t stream)
{
  const int*   ids    = (const int*)d_in[0];
  const int*   lens   = (const int*)d_in[1];
  const int*   labels = (const int*)d_in[2];
  const float* emb    = (const float*)d_in[3];
  const float* W_ih_f = (const float*)d_in[4];
  const float* W_hh_f = (const float*)d_in[5];
  const float* b_f    = (const float*)d_in[6];
  const float* W_ih_b = (const float*)d_in[7];
  const float* W_hh_b = (const float*)d_in[8];
  const float* b_b    = (const float*)d_in[9];
  const float* W_out  = (const float*)d_in[10];
  const float* b_out  = (const float*)d_in[11];
  const float* s_tr   = (const float*)d_in[12];
  const float* e_tr   = (const float*)d_in[13];
  const float* trans  = (const float*)d_in[14];
  float* out = (float*)d_out;

  float* ws = (float*)d_ws;
  float* xgc    = ws + OFF_XG;
  float* Wt     = ws + OFF_WT;
  float* hst    = ws + OFF_HS;
  float* cst    = ws + OFF_CS;
  float* emis_f = ws + OFF_EF;
  float* emis_b = ws + OFF_EB;
  float* numden = ws + OFF_ND;

  wtrans_kernel<<<128, 1024, 0, stream>>>(W_hh_f, W_hh_b, Wt);

  for (int ci = 0; ci < NCH; ++ci) {
    gemm_xg_kernel<<<512, 256, 0, stream>>>(ids, emb, W_ih_f, W_ih_b, b_f, b_b, xgc, ci);
    rec_chunk_kernel<<<128, 1024, 0, stream>>>(xgc, Wt, lens, hst, cst,
                                               emis_f, emis_b, W_out, b_out, ci);
  }

  crf_kernel<<<BB, 64, 0, stream>>>(emis_f, emis_b, labels, lens, s_tr, e_tr, trans, numden, out);
  loss_reduce_kernel<<<1, 256, 0, stream>>>(numden, out);
}

// Round 18
// 7161.885 us; speedup vs baseline: 2.5437x; 1.2511x over previous
//
#include <hip/hip_runtime.h>
#include <math.h>

#define TT 512
#define BB 256
#define EE 300
#define KK 9
#define HH 256
#define GG 1024
#define CHS 64
#define NCH (TT/CHS)

// ws offsets (floats)
#define OFF_XG ((size_t)0)                          // 2*CHS*BB*GG
#define OFF_WT (OFF_XG + (size_t)2*CHS*BB*GG)       // 2*64*1024 float4
#define OFF_HS (OFF_WT + (size_t)2*64*1024*4)
#define OFF_CS (OFF_HS + (size_t)2*BB*HH)
#define OFF_EF (OFF_CS + (size_t)2*BB*HH)
#define OFF_EB (OFF_EF + (size_t)BB*TT*KK)
#define OFF_ND (OFF_EB + (size_t)BB*TT*KK)

// NOTE: macro params must NOT be named x/y/z/w (round-6 preprocessor bug).
#define DOT4(a_,b_) ((a_).x*(b_).x + (a_).y*(b_).y + (a_).z*(b_).z + (a_).w*(b_).w)
#define FMA4(acc_, w_, h_) do { \
    acc_ = fmaf((w_).x, (h_).x, acc_); \
    acc_ = fmaf((w_).y, (h_).y, acc_); \
    acc_ = fmaf((w_).z, (h_).z, acc_); \
    acc_ = fmaf((w_).w, (h_).w, acc_); } while (0)

// ---------------- W_hh transpose/pack: Wt[dir][k4][row] (k-major; r10: native-layout
// lane-scattered reads collapse to HBM — keep packed) ----------------
__global__ __launch_bounds__(1024) void wtrans_kernel(
    const float* __restrict__ Wf, const float* __restrict__ Wb, float* __restrict__ Wt)
{
  int idx = blockIdx.x * 1024 + threadIdx.x;
  int dir = idx >> 16;
  int r   = (idx >> 6) & 1023;
  int k4  = idx & 63;
  const float* W = dir ? Wb : Wf;
  float4 v = *(const float4*)&W[(size_t)r * HH + k4 * 4];
  ((float4*)Wt)[(size_t)dir * 65536 + (size_t)k4 * 1024 + r] = v;
}

// ---------------- xg chunk GEMM: grid 512 (r14 verbatim — ~75% of f32 peak) ----------------
__global__ __launch_bounds__(256) void gemm_xg_kernel(
    const int* __restrict__ ids, const float* __restrict__ emb,
    const float* __restrict__ W_ih_f, const float* __restrict__ W_ih_b,
    const float* __restrict__ b_f, const float* __restrict__ b_b,
    float* __restrict__ xgc, int ci)
{
  __shared__ float As[60][132];
  __shared__ float Ws[60][132];
  __shared__ int tokid[128];
  const int tid = threadIdx.x;
  const int bx  = blockIdx.x;
  const int dir = bx >> 8;
  const int rem = bx & 255;
  const int rt  = rem & 127;
  const int nth = rem >> 7;            // nt half: 0 -> tiles 0..3, 1 -> tiles 4..7
  const float* W_ih = dir ? W_ih_b : W_ih_f;
  const float* bias = dir ? b_b : b_f;

  if (tid < 128) {
    int m = rt * 128 + tid;
    int sidx = ci * CHS + (m >> 8);
    int t = dir ? (TT - 1 - sidx) : sidx;
    tokid[tid] = ids[t * BB + (m & 255)];
  }
  __syncthreads();

  const int ty = tid >> 4, tx = tid & 15;
  for (int nt = nth * 4; nt < nth * 4 + 4; ++nt) {
    float acc[8][8];
    #pragma unroll
    for (int a_ = 0; a_ < 8; ++a_)
      #pragma unroll
      for (int b_ = 0; b_ < 8; ++b_) acc[a_][b_] = 0.f;

    for (int kc = 0; kc < 5; ++kc) {
      __syncthreads();
      for (int i = tid; i < 128 * 15; i += 256) {
        int mm = i / 15, kq = i - mm * 15;
        float4 v = *(const float4*)&emb[(size_t)tokid[mm] * EE + kc * 60 + kq * 4];
        As[kq*4+0][mm] = v.x; As[kq*4+1][mm] = v.y;
        As[kq*4+2][mm] = v.z; As[kq*4+3][mm] = v.w;
      }
      for (int i = tid; i < 128 * 15; i += 256) {
        int nn = i / 15, kq = i - nn * 15;
        float4 v = *(const float4*)&W_ih[(size_t)(nt*128+nn) * EE + kc * 60 + kq * 4];
        Ws[kq*4+0][nn] = v.x; Ws[kq*4+1][nn] = v.y;
        Ws[kq*4+2][nn] = v.z; Ws[kq*4+3][nn] = v.w;
      }
      __syncthreads();
      for (int kk = 0; kk < 60; ++kk) {
        float4 a0 = *(const float4*)&As[kk][ty*8];
        float4 a1 = *(const float4*)&As[kk][ty*8+4];
        float4 w0 = *(const float4*)&Ws[kk][tx*8];
        float4 w1 = *(const float4*)&Ws[kk][tx*8+4];
        float av[8]  = {a0.x,a0.y,a0.z,a0.w,a1.x,a1.y,a1.z,a1.w};
        float wv8[8] = {w0.x,w0.y,w0.z,w0.w,w1.x,w1.y,w1.z,w1.w};
        #pragma unroll
        for (int im = 0; im < 8; ++im)
          #pragma unroll
          for (int in = 0; in < 8; ++in) acc[im][in] += av[im] * wv8[in];
      }
    }
    #pragma unroll
    for (int im = 0; im < 8; ++im) {
      int m = ty*8 + im;
      int n = nt*128 + tx*8;
      float4 o0, o1;
      o0.x = acc[im][0] + bias[n+0]; o0.y = acc[im][1] + bias[n+1];
      o0.z = acc[im][2] + bias[n+2]; o0.w = acc[im][3] + bias[n+3];
      o1.x = acc[im][4] + bias[n+4]; o1.y = acc[im][5] + bias[n+5];
      o1.z = acc[im][6] + bias[n+6]; o1.w = acc[im][7] + bias[n+7];
      float* dst = &xgc[(size_t)(dir*16384 + rt*128 + m) * GG + n];
      *(float4*)dst = o0; *(float4*)(dst+4) = o1;
    }
  }
}

// ---------------- recurrence: r14 structure + LDS-resident W TAIL (iters 14-15) ----------------
// Register-neutral vs r14: streamed loop is r14's depth-2 pattern truncated at i=13 (same
// w/n liveness); LDS tail loads after prefetch regs die. FMA order i=0..15 unchanged ->
// bit-identical gates. Streamed W 1MB -> 0.875MB/step.
__global__ __launch_bounds__(1024, 1) void rec_chunk_kernel(
    const float* __restrict__ xgc, const float* __restrict__ Wt,
    const int* __restrict__ lens,
    float* __restrict__ hst, float* __restrict__ cst,
    float* __restrict__ emisf, float* __restrict__ emisb,
    const float* __restrict__ W_out, const float* __restrict__ b_out, int ci)
{
  __shared__ __align__(16) float hring[2][2][272];   // skew: float k at k+(k>>6)*4
  __shared__ __align__(16) float Wo[KK][256];
  __shared__ __align__(16) float4 WL[2 * 4104];      // iters 14-15: [j][kseg(pad 1026)][row]

  const int tid  = threadIdx.x;
  const int bid  = blockIdx.x;
  const int dir  = (bid & 7) >> 2;              // XCD-partitioned (perf-only heuristic)
  const int grp  = (bid >> 3) * 4 + (bid & 3);
  const int b0   = grp * 2;
  const int lane = tid & 63;
  const int wv   = tid >> 6;
  const int rg   = wv * 16 + (lane & 15);
  const int kseg = (lane >> 4) & 3;
  const bool cellLane = (lane & 48) == 0;
  float* emis = dir ? emisb : emisf;

  for (int i = tid; i < KK * 64; i += 1024) {
    int k = i >> 6, q = i & 63;
    *(float4*)&Wo[k][q*4] = *(const float4*)&W_out[(size_t)k * 512 + dir*256 + q*4];
  }

  // stage LDS-resident W slices (k-iterations 14 and 15), coalesced, once per chunk
  {
    const float4* wtd = (const float4*)Wt + (size_t)dir * 65536;
    for (int i = tid; i < 8192; i += 1024) {
      int j   = i >> 12;
      int ks  = (i >> 10) & 3;
      int row = i & 1023;
      WL[j * 4104 + ks * 1026 + row] = wtd[(size_t)(ks * 16 + 14 + j) * 1024 + row];
    }
  }

  int eb = 0, ek = 0, es = 0;
  const bool edo = tid < 2 * KK * 16;
  if (edo) { int q = tid; eb = q / 144; q -= eb * 144; ek = q >> 4; es = q & 15; }
  const float ebias = (edo && dir == 0) ? b_out[ek] : 0.f;

  int len2[2];
  #pragma unroll
  for (int b = 0; b < 2; ++b) len2[b] = lens[b0 + b];

  float creg[2] = {0.f,0.f}, hreg[2] = {0.f,0.f};
  if (cellLane) {
    if (ci > 0) {
      #pragma unroll
      for (int b = 0; b < 2; ++b) {
        hreg[b] = hst[((size_t)dir*BB + b0 + b) * HH + rg];
        creg[b] = cst[((size_t)dir*BB + b0 + b) * HH + rg];
      }
    }
    #pragma unroll
    for (int b = 0; b < 2; ++b)
      hring[0][b][rg + ((rg >> 6) << 2)] = hreg[b];
  }
  __syncthreads();

  const float4* wp = (const float4*)Wt + (size_t)dir * 65536
                   + (size_t)(kseg * 16) * 1024 + rg;
  const int wlbase = kseg * 1026 + rg;

  for (int sl = 0; sl < CHS; ++sl) {
    const int s = ci * CHS + sl;
    const int t = dir ? (TT - 1 - s) : s;
    const int cur = sl & 1, nxt = cur ^ 1;

    // xg prefetch (cell lanes; nontemporal — read-once stream)
    float xv[4][2];
    if (cellLane) {
      const float* xb = xgc + ((size_t)dir*(CHS*BB) + (size_t)sl*BB + b0) * GG + rg;
      #pragma unroll
      for (int q = 0; q < 4; ++q)
        #pragma unroll
        for (int b = 0; b < 2; ++b)
          xv[q][b] = __builtin_nontemporal_load(&xb[(size_t)b * GG + q * 256]);
    }

    // ---- GEMM over this thread's 64-k slice: i=0..13 streamed (depth-2), i=14..15 LDS ----
    float acc[4][2];
    #pragma unroll
    for (int q = 0; q < 4; ++q) { acc[q][0] = 0.f; acc[q][1] = 0.f; }

    const float4* hb = (const float4*)&hring[0][0][0] + cur * (2*68) + kseg * 17;
    float4 w0 = wp[0], w1 = wp[256], w2 = wp[512], w3 = wp[768];
    #pragma unroll 5
    for (int i = 0; i < 13; ++i) {
      const float4* wn = wp + (size_t)(i + 1) * 1024;
      float4 n0 = wn[0], n1 = wn[256], n2 = wn[512], n3 = wn[768];
      float4 h0 = hb[i], h1 = hb[68 + i];
      FMA4(acc[0][0], w0, h0); FMA4(acc[0][1], w0, h1);
      FMA4(acc[1][0], w1, h0); FMA4(acc[1][1], w1, h1);
      FMA4(acc[2][0], w2, h0); FMA4(acc[2][1], w2, h1);
      FMA4(acc[3][0], w3, h0); FMA4(acc[3][1], w3, h1);
      w0 = n0; w1 = n1; w2 = n2; w3 = n3;
    }
    {
      // i = 13 (last streamed; no prefetch)
      float4 h0 = hb[13], h1 = hb[68 + 13];
      FMA4(acc[0][0], w0, h0); FMA4(acc[0][1], w0, h1);
      FMA4(acc[1][0], w1, h0); FMA4(acc[1][1], w1, h1);
      FMA4(acc[2][0], w2, h0); FMA4(acc[2][1], w2, h1);
      FMA4(acc[3][0], w3, h0); FMA4(acc[3][1], w3, h1);
    }
    // ---- i = 14..15: LDS-resident (prefetch regs dead; temps reuse their slots) ----
    #pragma unroll
    for (int i = 14; i < 16; ++i) {
      const float4* wl = &WL[(i - 14) * 4104 + wlbase];
      float4 v0 = wl[0], v1 = wl[256], v2 = wl[512], v3 = wl[768];
      float4 h0 = hb[i], h1 = hb[68 + i];
      FMA4(acc[0][0], v0, h0); FMA4(acc[0][1], v0, h1);
      FMA4(acc[1][0], v1, h0); FMA4(acc[1][1], v1, h1);
      FMA4(acc[2][0], v2, h0); FMA4(acc[2][1], v2, h1);
      FMA4(acc[3][0], v3, h0); FMA4(acc[3][1], v3, h1);
    }

    // ---- reduce k-slices across lane bits 4-5 ----
    #pragma unroll
    for (int q = 0; q < 4; ++q)
      #pragma unroll
      for (int b = 0; b < 2; ++b) {
        float v = acc[q][b];
        v += __shfl_xor(v, 16);
        v += __shfl_xor(v, 32);
        acc[q][b] = v;
      }

    // ---- cell update (lanes l<16 hold full gates for their rg) ----
    if (cellLane) {
      #pragma unroll
      for (int b = 0; b < 2; ++b) {
        float gi = acc[0][b] + xv[0][b];
        float gf = acc[1][b] + xv[1][b];
        float gg = acc[2][b] + xv[2][b];
        float go = acc[3][b] + xv[3][b];
        float si = 1.f / (1.f + expf(-gi));
        float sf = 1.f / (1.f + expf(-gf));
        float so = 1.f / (1.f + expf(-go));
        float cn = sf * creg[b] + si * tanhf(gg);
        float hn = so * tanhf(cn);
        bool m = t < len2[b];
        hreg[b] = m ? hn : hreg[b];
        creg[b] = m ? cn : creg[b];
        hring[nxt][b][rg + ((rg >> 6) << 2)] = hreg[b];
      }
    }
    __syncthreads();

    // ---- fused emission for this timestep (reads hring[nxt]); NT store ----
    if (edo) {
      float r = 0.f;
      #pragma unroll
      for (int i4 = 0; i4 < 4; ++i4) {
        float4 h4 = *(const float4*)&hring[nxt][eb][es*4 + i4*68];
        float4 w4 = *(const float4*)&Wo[ek][es*4 + i4*64];
        r += DOT4(h4, w4);
      }
      r += __shfl_xor(r, 8); r += __shfl_xor(r, 4);
      r += __shfl_xor(r, 2); r += __shfl_xor(r, 1);
      if (es == 0)
        __builtin_nontemporal_store(r + ebias,
            &emis[((size_t)(b0 + eb) * TT + t) * KK + ek]);
    }
  }

  if (cellLane) {
    #pragma unroll
    for (int b = 0; b < 2; ++b) {
      hst[((size_t)dir*BB + b0 + b) * HH + rg] = hreg[b];
      cst[((size_t)dir*BB + b0 + b) * HH + rg] = creg[b];
    }
  }
}

// ---------------- CRF (identical numerics to rounds 1-17) ----------------
__global__ __launch_bounds__(64) void crf_kernel(
    const float* __restrict__ emis_f, const float* __restrict__ emis_b2,
    const int* __restrict__ labels, const int* __restrict__ lens,
    const float* __restrict__ start_trans, const float* __restrict__ end_trans,
    const float* __restrict__ trans,
    float* __restrict__ numden, float* __restrict__ outp)
{
  const int b = blockIdx.x;
  const int lane = threadIdx.x;
  __shared__ __align__(16) float em[TT * KK];
  __shared__ unsigned char hist[TT * KK];
  const float4* ef = (const float4*)(emis_f + (size_t)b * TT * KK);
  const float4* eb = (const float4*)(emis_b2 + (size_t)b * TT * KK);
  for (int i = lane; i < TT*KK/4; i += 64) {
    float4 a = ef[i], c = eb[i];
    float4 o; o.x = a.x+c.x; o.y = a.y+c.y; o.z = a.z+c.z; o.w = a.w+c.w;
    ((float4*)em)[i] = o;
  }
  const int len = lens[b];
  const int k = lane < KK ? lane : KK-1;
  float tc[KK];
  #pragma unroll
  for (int jj = 0; jj < KK; ++jj) tc[jj] = trans[jj*KK + k];
  __syncthreads();

  float nacc = 0.f;
  for (int t = lane; t < TT; t += 64) {
    int lt = labels[t*BB + b];
    if (t == 0) nacc += start_trans[lt] + em[lt];
    else if (t < len) nacc += trans[labels[(t-1)*BB + b]*KK + lt] + em[t*KK + lt];
  }
  if (lane == 0) nacc += end_trans[labels[(size_t)(len-1)*BB + b]];
  #pragma unroll
  for (int off = 32; off; off >>= 1) nacc += __shfl_down(nacc, off);

  float alpha[KK], score[KK];
  #pragma unroll
  for (int jj = 0; jj < KK; ++jj) {
    float v = start_trans[jj] + em[jj];
    alpha[jj] = v; score[jj] = v;
  }
  for (int t = 1; t < TT; ++t) {
    float av[KK]; float mx = -1e30f;
    #pragma unroll
    for (int jj = 0; jj < KK; ++jj) { av[jj] = alpha[jj] + tc[jj]; mx = fmaxf(mx, av[jj]); }
    float ssum = 0.f;
    #pragma unroll
    for (int jj = 0; jj < KK; ++jj) ssum += expf(av[jj] - mx);
    float e_tk = em[t*KK + k];
    float na = mx + logf(ssum) + e_tk;
    float best = -1e30f; int bj = 0;
    #pragma unroll
    for (int jj = 0; jj < KK; ++jj) {
      float sv = score[jj] + tc[jj];
      if (sv > best) { best = sv; bj = jj; }
    }
    float ns = best + e_tk;
    bool msk = t < len;
    na = msk ? na : alpha[k];
    ns = msk ? ns : score[k];
    if (lane < KK) hist[(t-1)*KK + lane] = (unsigned char)bj;
    #pragma unroll
    for (int jj = 0; jj < KK; ++jj) { alpha[jj] = __shfl(na, jj); score[jj] = __shfl(ns, jj); }
  }
  float dm = -1e30f;
  #pragma unroll
  for (int jj = 0; jj < KK; ++jj) dm = fmaxf(dm, alpha[jj] + end_trans[jj]);
  float dsum = 0.f;
  #pragma unroll
  for (int jj = 0; jj < KK; ++jj) dsum += expf(alpha[jj] + end_trans[jj] - dm);
  float denom = dm + logf(dsum);
  int bl_ = 0; float bs = -1e30f;
  #pragma unroll
  for (int jj = 0; jj < KK; ++jj) {
    float v = score[jj] + end_trans[jj];
    if (v > bs) { bs = v; bl_ = jj; }
  }
  if (lane == 0) numden[b] = nacc - denom;
  __syncthreads();
  if (lane == 0) {
    int tag = bl_;
    outp[1 + (size_t)(TT-1)*BB + b] = ((TT-1) < len) ? (float)bl_ : 0.f;
    for (int s = TT-2; s >= 0; --s) {
      tag = ((s+1) < len) ? (int)hist[s*KK + tag] : bl_;
      outp[1 + (size_t)s*BB + b] = (s < len) ? (float)tag : 0.f;
    }
  }
}

__global__ __launch_bounds__(256) void loss_reduce_kernel(
    const float* __restrict__ numden, float* __restrict__ out)
{
  __shared__ float sh[256];
  int tid = threadIdx.x;
  sh[tid] = numden[tid];
  __syncthreads();
  for (int s = 128; s > 0; s >>= 1) {
    if (tid < s) sh[tid] += sh[tid + s];
    __syncthreads();
  }
  if (tid == 0) out[0] = -sh[0];
}

extern "C" void kernel_launch(void* const* d_in, const int* in_sizes, int n_in,
                              void* d_out, int out_size, void* d_ws, size_t ws_size,
                              hipStream_t stream)
{
  const int*   ids    = (const int*)d_in[0];
  const int*   lens   = (const int*)d_in[1];
  const int*   labels = (const int*)d_in[2];
  const float* emb    = (const float*)d_in[3];
  const float* W_ih_f = (const float*)d_in[4];
  const float* W_hh_f = (const float*)d_in[5];
  const float* b_f    = (const float*)d_in[6];
  const float* W_ih_b = (const float*)d_in[7];
  const float* W_hh_b = (const float*)d_in[8];
  const float* b_b    = (const float*)d_in[9];
  const float* W_out  = (const float*)d_in[10];
  const float* b_out  = (const float*)d_in[11];
  const float* s_tr   = (const float*)d_in[12];
  const float* e_tr   = (const float*)d_in[13];
  const float* trans  = (const float*)d_in[14];
  float* out = (float*)d_out;

  float* ws = (float*)d_ws;
  float* xgc    = ws + OFF_XG;
  float* Wt     = ws + OFF_WT;
  float* hst    = ws + OFF_HS;
  float* cst    = ws + OFF_CS;
  float* emis_f = ws + OFF_EF;
  float* emis_b = ws + OFF_EB;
  float* numden = ws + OFF_ND;

  wtrans_kernel<<<128, 1024, 0, stream>>>(W_hh_f, W_hh_b, Wt);

  for (int ci = 0; ci < NCH; ++ci) {
    gemm_xg_kernel<<<512, 256, 0, stream>>>(ids, emb, W_ih_f, W_ih_b, b_f, b_b, xgc, ci);
    rec_chunk_kernel<<<256, 1024, 0, stream>>>(xgc, Wt, lens, hst, cst,
                                               emis_f, emis_b, W_out, b_out, ci);
  }

  crf_kernel<<<BB, 64, 0, stream>>>(emis_f, emis_b, labels, lens, s_tr, e_tr, trans, numden, out);
  loss_reduce_kernel<<<1, 256, 0, stream>>>(numden, out);
}